// Round 9
// baseline (217.686 us; speedup 1.0000x reference)
//
#include <hip/hip_runtime.h>
#include <hip/hip_fp16.h>
#include <math.h>

#define N_NODES 40000
#define N_EDGES 640000
#define DIM     128
#define N_GRAPHS 64
#define N_CLS   100
#define N_LAYERS 3
#define EPSN    1e-12f

// ---------------- CSR build ----------------

// counts AND intra-node position (so scatter needs no atomics)
__global__ void k_count(const int* __restrict__ dst, int* __restrict__ counts,
                        int* __restrict__ posw) {
    int e = blockIdx.x * blockDim.x + threadIdx.x;
    if (e < N_EDGES) posw[e] = atomicAdd(&counts[dst[e]], 1);
}

#define SCAN_T 1024
#define SCAN_V 40   // SCAN_T * SCAN_V >= N_NODES ; N_NODES/SCAN_V = 1000 exact
__global__ void k_scan(const int* __restrict__ counts, int* __restrict__ offsets) {
    __shared__ int lds[SCAN_T];
    int t = threadIdx.x;
    int base = t * SCAN_V;
    int tsum = 0;
    if (base < N_NODES) {
        for (int k = 0; k < SCAN_V; ++k) tsum += counts[base + k];
    }
    lds[t] = tsum; __syncthreads();
    int x = tsum;
    for (int off = 1; off < SCAN_T; off <<= 1) {
        int y = (t >= off) ? lds[t - off] : 0;
        __syncthreads();
        x += y;
        lds[t] = x;
        __syncthreads();
    }
    int excl = x - tsum;
    if (base < N_NODES) {
        int run = excl;
        for (int k = 0; k < SCAN_V; ++k) {
            offsets[base + k] = run;
            run += counts[base + k];
        }
    }
    if (t == (N_NODES / SCAN_V)) offsets[N_NODES] = excl;  // total = E
}

__global__ void k_scatter(const int* __restrict__ src, const int* __restrict__ dst,
                          const int* __restrict__ offsets, const int* __restrict__ posw,
                          int* __restrict__ csr_src) {
    int e = blockIdx.x * blockDim.x + threadIdx.x;
    if (e >= N_EDGES) return;
    csr_src[offsets[dst[e]] + posw[e]] = src[e];
}

// ---------------- per-layer kernels ----------------

// one wave per node: inv[v] = 1/(||h_v||+eps) AND pack the f32 input row into
// the fp16 gather table. Lane l owns elements [2l, 2l+1].
__global__ void k_norm(const float* __restrict__ h, float* __restrict__ inv,
                       __half2* __restrict__ hh) {
    int node = (blockIdx.x * blockDim.x + threadIdx.x) >> 6;
    int lane = threadIdx.x & 63;
    if (node >= N_NODES) return;
    const float2* r2 = (const float2*)(h + (size_t)node * DIM);
    float2 v = r2[lane];
    float ss = v.x * v.x + v.y * v.y;
    #pragma unroll
    for (int o = 32; o; o >>= 1) ss += __shfl_xor(ss, o);
    if (lane == 0) inv[node] = 1.0f / (sqrtf(ss) + EPSN);
    hh[(size_t)node * 64 + lane] = __floats2half2_rn(v.x, v.y);
}

// Fused edge-score + segment-softmax + aggregate on the fp16 table.
// One wave per node; 4 groups of 16 lanes; lane t owns features [8t..8t+7].
// Edge indices for the whole node are PRELOADED coalesced (one lane-strided
// load) and distributed via __shfl, so each batch of 16 edges (4 per group)
// issues 4 independent row gathers per lane with no dependent index loads.
// All math f32 (fp16 storage only). Scores = beta*cosine in [-1,1] -> exp
// bounded, no max-subtraction needed (softmax shift-invariance).
// LAST layer: per-block LDS pool reduction + atomicAdd into hgsum.
union H8 { int4 i4; __half2 h2[4]; };

__device__ __forceinline__ void cvt8(const H8& u, float* f) {
    #pragma unroll
    for (int k = 0; k < 4; ++k) {
        float2 v = __half22float2(u.h2[k]);
        f[2 * k]     = v.x;
        f[2 * k + 1] = v.y;
    }
}

template <bool LAST>
__global__ void k_fused(const int4* __restrict__ hh_in,      // fp16 table, 16 int4/row
                        const float* __restrict__ inv_in,
                        const int* __restrict__ csr_src,
                        const int* __restrict__ offsets,
                        const float* __restrict__ betas, int layer,
                        int4* __restrict__ hh_out,            // fp16 table (if !LAST)
                        float* __restrict__ inv_out,
                        const int* __restrict__ gid,          // (if LAST)
                        float* __restrict__ hgsum) {          // (if LAST)
    int node = (blockIdx.x * blockDim.x + threadIdx.x) >> 6;  // grid covers exactly N_NODES
    int lane = threadIdx.x & 63;
    int grp = lane >> 4;   // 0..3
    int t   = lane & 15;   // feature sublane: owns features [8t..8t+7]

    int off = offsets[node];
    int deg = offsets[node + 1] - off;

    size_t nrow16 = (size_t)node * 16;
    H8 selfu; selfu.i4 = hh_in[nrow16 + t];
    float hd[8]; cvt8(selfu, hd);
    float bi = betas[layer] * inv_in[node];

    float dsum = 0.f;
    float ac[8];
    #pragma unroll
    for (int k = 0; k < 8; ++k) ac[k] = 0.f;

    if (deg > 0) {
        int last = deg - 1;
        // ---- preload up to 64 edge indices + inv-norms, lane-parallel ----
        int   myidx = csr_src[off + min(lane, last)];   // coalesced
        float myiv  = inv_in[myidx];                    // gather (dupes broadcast)

        int dmax = min(deg, 64);
        for (int jb = 0; jb < dmax; jb += 16) {
            bool v[4]; int s[4]; float iv[4];
            #pragma unroll
            for (int k = 0; k < 4; ++k) {
                int eidx = jb + (k << 2) + grp;
                v[k] = eidx <= last;
                int ec = v[k] ? eidx : last;
                s[k]  = __shfl(myidx, ec);
                iv[k] = __shfl(myiv, ec);
            }
            H8 u[4];
            #pragma unroll
            for (int k = 0; k < 4; ++k) u[k].i4 = hh_in[(size_t)s[k] * 16 + t];
            float f[4][8], pp[4];
            #pragma unroll
            for (int k = 0; k < 4; ++k) cvt8(u[k], f[k]);
            #pragma unroll
            for (int k = 0; k < 4; ++k) {
                float p = 0.f;
                #pragma unroll
                for (int q = 0; q < 8; ++q) p += f[k][q] * hd[q];
                pp[k] = p;
            }
            #pragma unroll
            for (int o = 8; o; o >>= 1) {
                #pragma unroll
                for (int k = 0; k < 4; ++k) pp[k] += __shfl_xor(pp[k], o);
            }
            float w[4];
            #pragma unroll
            for (int k = 0; k < 4; ++k) {
                w[k] = v[k] ? __expf(bi * iv[k] * pp[k]) : 0.f;
                dsum += w[k];
            }
            #pragma unroll
            for (int q = 0; q < 8; ++q)
                ac[q] += w[0] * f[0][q] + w[1] * f[1][q]
                       + w[2] * f[2][q] + w[3] * f[3][q];
        }

        // ---- rare fallback: deg > 64 (direct loads, 4 edges per pass) ----
        for (int jb = 64; jb < deg; jb += 4) {
            int eidx = jb + grp;
            bool vv = eidx <= last;
            int ec = vv ? eidx : last;
            int ss = csr_src[off + ec];
            float iiv = inv_in[ss];
            H8 u; u.i4 = hh_in[(size_t)ss * 16 + t];
            float f1[8]; cvt8(u, f1);
            float p = 0.f;
            #pragma unroll
            for (int q = 0; q < 8; ++q) p += f1[q] * hd[q];
            #pragma unroll
            for (int o = 8; o; o >>= 1) p += __shfl_xor(p, o);
            float ww = vv ? __expf(bi * iiv * p) : 0.f;
            dsum += ww;
            #pragma unroll
            for (int q = 0; q < 8; ++q) ac[q] += ww * f1[q];
        }

        // merge the 4 group partials (plain sums)
        #pragma unroll
        for (int o = 16; o < 64; o <<= 1) {
            dsum += __shfl_xor(dsum, o);
            #pragma unroll
            for (int k = 0; k < 8; ++k) ac[k] += __shfl_xor(ac[k], o);
        }
        float invd = 1.0f / dsum;
        #pragma unroll
        for (int k = 0; k < 8; ++k) ac[k] *= invd;
    }

    if (LAST) {
        // fused AvgPooling numerator: block = 4 nodes (sorted gid)
        __shared__ float spool[DIM];
        __shared__ int sg[4];
        int tid = threadIdx.x;
        int g = gid[node];
        if (lane == 0) sg[tid >> 6] = g;
        if (tid < DIM) spool[tid] = 0.f;
        __syncthreads();
        bool uni = (sg[0] == sg[1]) && (sg[1] == sg[2]) && (sg[2] == sg[3]);
        if (uni) {
            if (grp == 0) {
                #pragma unroll
                for (int k = 0; k < 8; ++k) atomicAdd(&spool[8 * t + k], ac[k]);
            }
            __syncthreads();
            if (tid < DIM) atomicAdd(&hgsum[(size_t)sg[0] * DIM + tid], spool[tid]);
        } else {
            if (grp == 0) {
                #pragma unroll
                for (int k = 0; k < 8; ++k)
                    atomicAdd(&hgsum[(size_t)g * DIM + 8 * t + k], ac[k]);
            }
        }
    } else {
        if (grp == 0) {
            H8 w;
            #pragma unroll
            for (int k = 0; k < 4; ++k)
                w.h2[k] = __floats2half2_rn(ac[2 * k], ac[2 * k + 1]);
            hh_out[nrow16 + t] = w.i4;
        }
        // fused inv-norm of the output row (for next layer's scores)
        float ss = 0.f;
        #pragma unroll
        for (int k = 0; k < 8; ++k) ss += ac[k] * ac[k];
        #pragma unroll
        for (int o = 8; o; o >>= 1) ss += __shfl_xor(ss, o);
        if (lane == 0) inv_out[node] = 1.0f / (sqrtf(ss) + EPSN);
    }
}

// ---------------- readout ----------------

// one block (128 threads) per graph; counts via binary search on sorted gid
__global__ void k_cls(const float* __restrict__ hgsum, const int* __restrict__ gid,
                      const float* __restrict__ W, const float* __restrict__ b,
                      float* __restrict__ out) {
    int g = blockIdx.x;
    int c = threadIdx.x;
    __shared__ float invc_s;
    if (c == 0) {
        int lo = 0, hi = N_NODES;
        while (lo < hi) { int mid = (lo + hi) >> 1; if (gid[mid] < g) lo = mid + 1; else hi = mid; }
        int start = lo;
        lo = 0; hi = N_NODES;
        while (lo < hi) { int mid = (lo + hi) >> 1; if (gid[mid] < g + 1) lo = mid + 1; else hi = mid; }
        invc_s = 1.0f / fmaxf((float)(lo - start), 1.0f);
    }
    __syncthreads();
    if (c >= N_CLS) return;
    float acc = 0.f;
    #pragma unroll 8
    for (int d = 0; d < DIM; ++d) acc += hgsum[g * DIM + d] * W[d * N_CLS + c];
    out[g * N_CLS + c] = b[c] + acc * invc_s;
}

// ---------------- launch ----------------

extern "C" void kernel_launch(void* const* d_in, const int* in_sizes, int n_in,
                              void* d_out, int out_size, void* d_ws, size_t ws_size,
                              hipStream_t stream) {
    const float* h_in  = (const float*)d_in[0];
    const int*   src   = (const int*)  d_in[1];
    const int*   dst   = (const int*)  d_in[2];
    const int*   gid   = (const int*)  d_in[3];
    const float* betas = (const float*)d_in[4];
    const float* W     = (const float*)d_in[5];
    const float* bcls  = (const float*)d_in[6];
    float* out = (float*)d_out;

    char* p = (char*)d_ws;
    int4*  hh0     = (int4*)p;  p += (size_t)N_NODES * DIM * 2;   // 10.24 MB fp16 table
    int4*  hh1     = (int4*)p;  p += (size_t)N_NODES * DIM * 2;   // 10.24 MB fp16 table
    float* inv0    = (float*)p; p += (size_t)N_NODES * 4;
    float* inv1    = (float*)p; p += (size_t)N_NODES * 4;
    // --- contiguous zero-init region (memset) ---
    int*   counts  = (int*)p;   p += (size_t)N_NODES * 4;
    float* hgsum   = (float*)p; p += (size_t)N_GRAPHS * DIM * 4;
    // --------------------------------------------
    int*   offsets = (int*)p;   p += (size_t)(N_NODES + 4) * 4;   // N+1 used, padded
    int*   posw    = (int*)p;   p += (size_t)N_EDGES * 4;
    int*   csr_src = (int*)p;   p += (size_t)N_EDGES * 4;

    const size_t ZERO_BYTES = (size_t)(N_NODES + N_GRAPHS * DIM) * 4;

    // ---- CSR build (src/dst constant across layers) ----
    hipMemsetAsync(counts, 0, ZERO_BYTES, stream);
    k_count<<<(N_EDGES + 255) / 256, 256, 0, stream>>>(dst, counts, posw);
    k_scan<<<1, SCAN_T, 0, stream>>>(counts, offsets);
    k_scatter<<<(N_EDGES + 255) / 256, 256, 0, stream>>>(src, dst, offsets, posw, csr_src);

    // ---- 3 AGNN layers on the fp16 table ----
    k_norm<<<N_NODES / 4, 256, 0, stream>>>(h_in, inv0, (__half2*)hh0);
    k_fused<false><<<N_NODES / 4, 256, 0, stream>>>(hh0, inv0, csr_src, offsets, betas, 0,
                                                    hh1, inv1, nullptr, nullptr);
    k_fused<false><<<N_NODES / 4, 256, 0, stream>>>(hh1, inv1, csr_src, offsets, betas, 1,
                                                    hh0, inv0, nullptr, nullptr);
    k_fused<true><<<N_NODES / 4, 256, 0, stream>>>(hh0, inv0, csr_src, offsets, betas, 2,
                                                   nullptr, nullptr, gid, hgsum);

    // ---- readout ----
    k_cls<<<N_GRAPHS, DIM, 0, stream>>>(hgsum, gid, W, bcls, out);
}